// Round 10
// baseline (268.458 us; speedup 1.0000x reference)
//
#include <hip/hip_runtime.h>
#include <hip/hip_fp16.h>
#include <stdint.h>

typedef _Float16 f16;
typedef _Float16 f16x8 __attribute__((ext_vector_type(8)));
typedef float    f32x4 __attribute__((ext_vector_type(4)));
typedef int      i32x4 __attribute__((ext_vector_type(4)));

#define NQ 8192
#define NK 8192
#define DD 512
#define DVV 512
#define LOG2E 1.44269504f
#define KT256 (NK / 256)   // 32 key-tiles

// ---- async global->LDS stage of 64 lanes x 16B (wave-uniform LDS base, per-lane global src) ----
__device__ __forceinline__ void stage16(const void* g, void* ldsbase, int lane) {
#if __has_builtin(__builtin_amdgcn_global_load_lds)
  __builtin_amdgcn_global_load_lds((const __attribute__((address_space(1))) void*)g,
                                   (__attribute__((address_space(3))) void*)ldsbase, 16, 0, 0);
#else
  ((i32x4*)ldsbase)[lane] = *(const i32x4*)g;
#endif
}

// ---- fp32 -> f16 plain (Q chunks and K) ----
__global__ void conv_f16k(const float* __restrict__ src, f16* __restrict__ dst, int n8) {
  int i = blockIdx.x * 256 + threadIdx.x;
  if (i >= n8) return;
  const float4* s4 = (const float4*)src;
  float4 a = s4[2 * i], b = s4[2 * i + 1];
  float vv[8] = {a.x, a.y, a.z, a.w, b.x, b.y, b.z, b.w};
  f16 h8[8];
#pragma unroll
  for (int j = 0; j < 8; ++j) h8[j] = (f16)vv[j];
  *(f16x8*)(dst + (size_t)i * 8) = *(f16x8*)h8;
}

// ---- V fp32 [key][dv] -> f16 transposed [dv][key] ----
__global__ void conv_vT(const float* __restrict__ v, f16* __restrict__ vT) {
  __shared__ float t[64][65];
  int k0 = blockIdx.x * 64, d0 = blockIdx.y * 64;
#pragma unroll
  for (int e = 0; e < 16; ++e) {
    int idx = threadIdx.x + e * 256;
    int kr = idx >> 6, dc = idx & 63;
    t[kr][dc] = v[(size_t)(k0 + kr) * DVV + d0 + dc];
  }
  __syncthreads();
  int dl = threadIdx.x >> 2, seg = (threadIdx.x & 3) * 16;
  f16 tmp[16];
#pragma unroll
  for (int c = 0; c < 16; ++c) tmp[c] = (f16)t[seg + c][dl];
  f16* dst = vT + (size_t)(d0 + dl) * NK + k0 + seg;
  *(f16x8*)dst = *(f16x8*)tmp;
  *(f16x8*)(dst + 8) = *(f16x8*)(tmp + 8);
}

// ---- K1: S = Q*K^T plain f16, 256x256 tile, BK=64, 8 waves (2Mx4N), double-buffered
//      128KB LDS, 8-phase schedule (4 phases/K-tile): per phase {ds_read quadrant,
//      (front-loaded stage), raw barrier, lgkmcnt(0)+sched_barrier, setprio 16-MFMA,
//      barrier}; flip waits own loads only. Epilogue: exp2 softmax + LDS-bounce to
//      TILE-BLOCKED s16 + transposed pm/ps (all R9-proven).
__global__ __launch_bounds__(512, 2) void qk_kernel(
    const f16* __restrict__ q16, const f16* __restrict__ k16,
    f16* __restrict__ s16, float* __restrict__ pmT, float* __restrict__ psT,
    int nrows) {
  __shared__ f16 LS[65536];           // mainloop: [buf][A 256x64 | B 256x64]; epilogue P[256][256]
  __shared__ float red[2][4][128];
  const int tid = threadIdx.x, lane = tid & 63, wid = tid >> 6;
  const int wr = wid >> 2, wc = wid & 3;   // 2(M) x 4(N)
  const int bx = blockIdx.x, by = blockIdx.y;
  const int lo16 = lane & 15, hi4 = lane >> 4;

  f32x4 acc[8][4] = {};

  // staging: per wave 4 A-units + 4 B-units of (8 rows x 128B); src pre-swizzled, LDS linear
  const int srw = lane >> 3, sc8 = (lane & 7) ^ srw;
  const f16* aptr[4]; const f16* bptr[4]; int adst[4], bdst[4];
#pragma unroll
  for (int u = 0; u < 4; ++u) {
    int r = wid * 32 + u * 8 + srw;
    aptr[u] = q16 + (size_t)(by * 256 + r) * DD + sc8 * 8;
    bptr[u] = k16 + (size_t)(bx * 256 + r) * DD + sc8 * 8;
    adst[u] = (wid * 32 + u * 8) * 64;
    bdst[u] = adst[u] + 16384;
  }
  // fragment offsets (conflict-free: 128B rows, unit ^ (row&7))
  int aoff[8][2], boff[4][2];
#pragma unroll
  for (int m = 0; m < 8; ++m)
#pragma unroll
    for (int kk = 0; kk < 2; ++kk) {
      int row = wr * 128 + m * 16 + lo16;
      aoff[m][kk] = row * 64 + (((kk * 4 + hi4) ^ (row & 7)) << 3);
    }
#pragma unroll
  for (int n = 0; n < 4; ++n)
#pragma unroll
    for (int kk = 0; kk < 2; ++kk) {
      int row = wc * 64 + n * 16 + lo16;
      boff[n][kk] = 16384 + row * 64 + (((kk * 4 + hi4) ^ (row & 7)) << 3);
    }

#define STG8(t2, buf)                                                       \
  do {                                                                      \
    _Pragma("unroll") for (int u = 0; u < 4; ++u) {                         \
      stage16(aptr[u] + (t2) * 64, LS + (buf) * 32768 + adst[u], lane);     \
      stage16(bptr[u] + (t2) * 64, LS + (buf) * 32768 + bdst[u], lane);     \
    }                                                                       \
  } while (0)

#define MFMA16(hh, kk)                                                      \
  do {                                                                      \
    __builtin_amdgcn_s_setprio(1);                                          \
    _Pragma("unroll") for (int mi = 0; mi < 4; ++mi)                        \
    _Pragma("unroll") for (int n = 0; n < 4; ++n)                           \
        acc[(hh) * 4 + mi][n] = __builtin_amdgcn_mfma_f32_16x16x32_f16(     \
            af[mi], bf[n], acc[(hh) * 4 + mi][n], 0, 0, 0);                 \
    __builtin_amdgcn_s_setprio(0);                                          \
    (void)(kk);                                                             \
  } while (0)

#define BAR()                                                               \
  do {                                                                      \
    asm volatile("" ::: "memory");                                          \
    __builtin_amdgcn_s_barrier();                                           \
    asm volatile("" ::: "memory");                                          \
  } while (0)

  // prologue
  STG8(0, 0);
  asm volatile("s_waitcnt vmcnt(0)" ::: "memory");
  BAR();

  for (int t = 0; t < 8; ++t) {
    const int cur = t & 1;
    const f16* Bb = LS + cur * 32768;
    f16x8 af[4], bf[4];

    // ---------- phase 0: (M-half 0, K-half 0) + front-loaded stage of tile t+1 ----------
#pragma unroll
    for (int n = 0; n < 4; ++n) bf[n] = *(const f16x8*)&Bb[boff[n][0]];
#pragma unroll
    for (int mi = 0; mi < 4; ++mi) af[mi] = *(const f16x8*)&Bb[aoff[mi][0]];
    if (t < 7) STG8(t + 1, cur ^ 1);
    BAR();
    asm volatile("s_waitcnt lgkmcnt(0)" ::: "memory");
    __builtin_amdgcn_sched_barrier(0);
    MFMA16(0, 0);
    BAR();

    // ---------- phase 1: (M-half 1, K-half 0), reuse bf ----------
#pragma unroll
    for (int mi = 0; mi < 4; ++mi) af[mi] = *(const f16x8*)&Bb[aoff[4 + mi][0]];
    BAR();
    asm volatile("s_waitcnt lgkmcnt(0)" ::: "memory");
    __builtin_amdgcn_sched_barrier(0);
    MFMA16(1, 0);
    BAR();

    // ---------- phase 2: (M-half 0, K-half 1) ----------
#pragma unroll
    for (int n = 0; n < 4; ++n) bf[n] = *(const f16x8*)&Bb[boff[n][1]];
#pragma unroll
    for (int mi = 0; mi < 4; ++mi) af[mi] = *(const f16x8*)&Bb[aoff[mi][1]];
    BAR();
    asm volatile("s_waitcnt lgkmcnt(0)" ::: "memory");
    __builtin_amdgcn_sched_barrier(0);
    MFMA16(0, 1);
    BAR();

    // ---------- phase 3: (M-half 1, K-half 1), reuse bf; flip ----------
#pragma unroll
    for (int mi = 0; mi < 4; ++mi) af[mi] = *(const f16x8*)&Bb[aoff[4 + mi][1]];
    BAR();
    asm volatile("s_waitcnt lgkmcnt(0)" ::: "memory");
    __builtin_amdgcn_sched_barrier(0);
    MFMA16(1, 1);
    // flip: own stage loads for t+1 (issued in phase 0, ~3 phases ago) must be done
    asm volatile("s_waitcnt vmcnt(0)" ::: "memory");
    BAR();
  }
#undef STG8
#undef MFMA16
#undef BAR

  __syncthreads();

  // ---- epilogue: tile-local softmax (exp2) ----
  float rmax[8][4];
#pragma unroll
  for (int i = 0; i < 8; ++i)
#pragma unroll
    for (int r = 0; r < 4; ++r) {
      float m = fmaxf(fmaxf(acc[i][0][r], acc[i][1][r]), fmaxf(acc[i][2][r], acc[i][3][r]));
#pragma unroll
      for (int d = 1; d < 16; d <<= 1) m = fmaxf(m, __shfl_xor(m, d, 64));
      rmax[i][r] = m;
    }
  if (lo16 == 0) {
#pragma unroll
    for (int i = 0; i < 8; ++i)
#pragma unroll
      for (int r = 0; r < 4; ++r) red[wr][wc][i * 16 + hi4 * 4 + r] = rmax[i][r];
  }
  __syncthreads();
  float pmv[8][4];
#pragma unroll
  for (int i = 0; i < 8; ++i)
#pragma unroll
    for (int r = 0; r < 4; ++r) {
      int rl = i * 16 + hi4 * 4 + r;
      pmv[i][r] = fmaxf(fmaxf(red[wr][0][rl], red[wr][1][rl]),
                        fmaxf(red[wr][2][rl], red[wr][3][rl]));
    }
  __syncthreads();
  // exp + row-sum; P into LS (reused as [256][256] f16, swizzle (kloc>>3)^(qloc&7))
  float rsum[8][4];
#pragma unroll
  for (int i = 0; i < 8; ++i)
#pragma unroll
    for (int r = 0; r < 4; ++r) {
      int qloc = wr * 128 + i * 16 + hi4 * 4 + r;
      int swz = (qloc & 7) << 3;
      float s = 0.f;
#pragma unroll
      for (int j = 0; j < 4; ++j) {
        float p = exp2f((acc[i][j][r] - pmv[i][r]) * LOG2E);
        s += p;
        int kloc = wc * 64 + j * 16 + lo16;
        LS[qloc * 256 + ((kloc & ~7) ^ swz) + (kloc & 7)] = (f16)p;
      }
#pragma unroll
      for (int d = 1; d < 16; d <<= 1) s += __shfl_xor(s, d, 64);
      rsum[i][r] = s;
    }
  if (lo16 == 0) {
#pragma unroll
    for (int i = 0; i < 8; ++i)
#pragma unroll
      for (int r = 0; r < 4; ++r) red[wr][wc][i * 16 + hi4 * 4 + r] = rsum[i][r];
  }
  __syncthreads();
  // pm/ps transposed store [bx][row]
  if (wc == 0 && lo16 == 0) {
#pragma unroll
    for (int i = 0; i < 8; ++i)
#pragma unroll
      for (int r = 0; r < 4; ++r) {
        int rl = i * 16 + hi4 * 4 + r;
        size_t grow = (size_t)(by * 256 + wr * 128 + rl);
        pmT[(size_t)bx * nrows + grow] = pmv[i][r];
        psT[(size_t)bx * nrows + grow] = red[wr][0][rl] + red[wr][1][rl] +
                                         red[wr][2][rl] + red[wr][3][rl];
      }
  }
  // TILE-BLOCKED coalesced s16 store: block writes private contiguous 128KB region.
  {
    const int q = tid >> 1, half = tid & 1;
    const int swz = (q & 7) << 3;
    f16* gdst = s16 + ((size_t)(by * KT256 + bx) << 16) + q * 256 + half * 128;
#pragma unroll
    for (int e = 0; e < 16; ++e) {
      int k0 = half * 128 + e * 8;
      f16x8 v = *(const f16x8*)&LS[q * 256 + (k0 ^ swz)];
      *(f16x8*)(gdst + e * 8) = v;
    }
  }
}

// ---- K2: per-row combine of 32 tile partials (transposed layout) ----
__global__ void red_kernel(const float* __restrict__ pmT, const float* __restrict__ psT,
                           float* __restrict__ coefT, int nrows) {
  int row = blockIdx.x * 8 + (threadIdx.x >> 5);
  int t = threadIdx.x & 31;
  float pmt = pmT[(size_t)t * nrows + row];
  float m = pmt;
#pragma unroll
  for (int d = 1; d < 32; d <<= 1) m = fmaxf(m, __shfl_xor(m, d, 32));
  float e = exp2f((pmt - m) * LOG2E);
  float l = psT[(size_t)t * nrows + row] * e;
#pragma unroll
  for (int d = 1; d < 32; d <<= 1) l += __shfl_xor(l, d, 32);
  coefT[(size_t)t * nrows + row] = e / l;
}

// ---- K3: O_partial = (coef*p16) @ V16^T. 128x128 tile, BK=64, K-split over blockIdx.z.
//      p16 read from TILE-BLOCKED layout. ----
__global__ __launch_bounds__(256, 2) void pv_kernel(
    const f16* __restrict__ p16, const float* __restrict__ coefT,
    const f16* __restrict__ vT, float* __restrict__ dst,
    int steps, size_t zstride, int nrows) {
  __shared__ f16 lsA[2][128 * 64];
  __shared__ f16 lsB[2][128 * 64];
  const int tid = threadIdx.x, lane = tid & 63, wid = tid >> 6;
  const int lo16 = lane & 15, hi4 = lane >> 4;
  const int wr = wid >> 1, wc = wid & 1;
  const int bx = blockIdx.x, by = blockIdx.y, bz = blockIdx.z;
  const int g0 = bz * steps;
  f32x4 acc[4][4] = {};

  const int arow0 = tid >> 3, acol = tid & 7;
  const int srw = lane >> 3;
  const int sc = (lane & 7) ^ srw;

  // tiled-layout base per u: tile row qt=r>>8, in-tile row qloc=r&255
  size_t qtb[4];
#pragma unroll
  for (int u = 0; u < 4; ++u) {
    int r = by * 128 + u * 32 + arow0;
    qtb[u] = ((size_t)(r >> 8) * KT256 << 16) + (size_t)(r & 255) * 256 + acol * 8;
  }

  f16x8 va[4];
  float scv[4];

#define PV_LOADA(g)                                                           \
  do {                                                                        \
    _Pragma("unroll") for (int u = 0; u < 4; ++u)                             \
        va[u] = *(const f16x8*)(p16 + qtb[u] + ((size_t)((g) >> 2) << 16) +   \
                                ((g) & 3) * 64);                              \
    _Pragma("unroll") for (int u = 0; u < 4; ++u)                             \
        scv[u] = coefT[(size_t)((g) >> 2) * nrows + by * 128 + u * 32 + arow0]; \
  } while (0)

  PV_LOADA(g0);
#pragma unroll
  for (int i = 0; i < 4; ++i) {
    int unit = wid * 4 + i;
    int row = unit * 8 + srw;
    stage16(vT + (size_t)(bx * 128 + row) * NK + (size_t)g0 * 64 + sc * 8,
            &lsB[0][unit * 512], lane);
  }
#pragma unroll
  for (int u = 0; u < 4; ++u) {
    int row = u * 32 + arow0;
    f16x8 vv = va[u] * (f16)scv[u];
    *(f16x8*)&lsA[0][row * 64 + ((acol ^ (row & 7)) << 3)] = vv;
  }
  __syncthreads();

  for (int s = 0; s < steps; ++s) {
    const int cur = s & 1, nxt = cur ^ 1;
    const int g = g0 + s;
    if (s + 1 < steps) {
      PV_LOADA(g + 1);
#pragma unroll
      for (int i = 0; i < 4; ++i) {
        int unit = wid * 4 + i;
        int row = unit * 8 + srw;
        stage16(vT + (size_t)(bx * 128 + row) * NK + (size_t)(g + 1) * 64 + sc * 8,
                &lsB[nxt][unit * 512], lane);
      }
    }
#pragma unroll
    for (int ks = 0; ks < 2; ++ks) {
      f16x8 af[4], bf[4];
#pragma unroll
      for (int i = 0; i < 4; ++i) {
        int row = wr * 64 + i * 16 + lo16;
        af[i] = *(const f16x8*)&lsA[cur][row * 64 + (((ks * 4 + hi4) ^ (row & 7)) << 3)];
      }
#pragma unroll
      for (int j = 0; j < 4; ++j) {
        int dv = wc * 64 + j * 16 + lo16;
        bf[j] = *(const f16x8*)&lsB[cur][dv * 64 + (((ks * 4 + hi4) ^ (dv & 7)) << 3)];
      }
#pragma unroll
      for (int i = 0; i < 4; ++i)
#pragma unroll
        for (int j = 0; j < 4; ++j)
          acc[i][j] = __builtin_amdgcn_mfma_f32_16x16x32_f16(af[i], bf[j], acc[i][j], 0, 0, 0);
    }
    if (s + 1 < steps) {
#pragma unroll
      for (int u = 0; u < 4; ++u) {
        int row = u * 32 + arow0;
        f16x8 vv = va[u] * (f16)scv[u];
        *(f16x8*)&lsA[nxt][row * 64 + ((acol ^ (row & 7)) << 3)] = vv;
      }
    }
    __syncthreads();
  }
#undef PV_LOADA

  float* o = dst + (size_t)bz * zstride;
#pragma unroll
  for (int i = 0; i < 4; ++i)
#pragma unroll
    for (int j = 0; j < 4; ++j)
#pragma unroll
      for (int r = 0; r < 4; ++r)
        o[(size_t)(by * 128 + wr * 64 + i * 16 + hi4 * 4 + r) * DVV +
          bx * 128 + wc * 64 + j * 16 + lo16] = acc[i][j][r];
}

// ---- K4: sum K-split partials ----
__global__ void reduce_out(const float* __restrict__ part, float* __restrict__ out,
                           int ks, size_t n4) {
  size_t i = (size_t)blockIdx.x * 256 + threadIdx.x;
  if (i >= n4) return;
  float4 a = ((const float4*)part)[i];
  for (int z = 1; z < ks; ++z) {
    float4 b = ((const float4*)(part + z * n4 * 4))[i];
    a.x += b.x; a.y += b.y; a.z += b.z; a.w += b.w;
  }
  ((float4*)out)[i] = a;
}

__global__ void zero_out(float* o, int n) {
  int i = blockIdx.x * 256 + threadIdx.x;
  if (i < n) o[i] = 0.f;
}

extern "C" void kernel_launch(void* const* d_in, const int* in_sizes, int n_in,
                              void* d_out, int out_size, void* d_ws, size_t ws_size,
                              hipStream_t stream) {
  (void)in_sizes; (void)n_in; (void)out_size;
  const float* Q = (const float*)d_in[0];
  const float* K = (const float*)d_in[1];
  const float* V = (const float*)d_in[2];
  float* out = (float*)d_out;

  const size_t sz16 = (size_t)NK * DD * 2;                  // 8 MB
  const size_t fixedB = 2 * sz16;                           // k16, vT
  const size_t perRow = 1024 + 32 * 4 * 3 + (size_t)NK * 2; // q16 + pmT/psT/coefT + s16 = 17792
  const size_t partB = (size_t)16384 * DVV * 4;             // 32 MB (ks*nc == 16384)
  int nc = 0;
  for (int cand = 8192; cand >= 1024; cand >>= 1)
    if (fixedB + (size_t)cand * perRow + partB <= ws_size) { nc = cand; break; }
  if (nc == 0) {
    zero_out<<<(NQ * DVV + 255) / 256, 256, 0, stream>>>(out, NQ * DVV);
    return;
  }
  const int ks = 16384 / nc;       // pv K-split so grid = 4 * (nc/128) * ks = 512 blocks
  const int steps = 128 / ks;      // 64-key steps per z

  char* w = (char*)d_ws;
  f16* k16 = (f16*)w;
  f16* vT = (f16*)(w + sz16);
  char* p = w + fixedB;
  f16* q16 = (f16*)p;       p += (size_t)nc * 1024;
  float* pmT = (float*)p;   p += (size_t)nc * 128;
  float* psT = (float*)p;   p += (size_t)nc * 128;
  float* coefT = (float*)p; p += (size_t)nc * 128;
  f16* s16 = (f16*)p;       p += (size_t)nc * NK * 2;
  float* part = (float*)p;

  conv_f16k<<<NK * DD / 8 / 256, 256, 0, stream>>>(K, k16, NK * DD / 8);
  conv_vT<<<dim3(NK / 64, DVV / 64), 256, 0, stream>>>(V, vT);

  for (int c = 0; c < NQ / nc; ++c) {
    conv_f16k<<<nc * DD / 8 / 256, 256, 0, stream>>>(Q + (size_t)c * nc * DD, q16, nc * DD / 8);
    qk_kernel<<<dim3(NK / 256, nc / 256), 512, 0, stream>>>(q16, k16, s16, pmT, psT, nc);
    red_kernel<<<nc / 8, 256, 0, stream>>>(pmT, psT, coefT, nc);
    pv_kernel<<<dim3(DVV / 128, nc / 128, ks), 256, 0, stream>>>(
        s16, coefT, vT, part, steps, (size_t)nc * DVV, nc);
    reduce_out<<<(int)(((size_t)nc * DVV / 4 + 255) / 256), 256, 0, stream>>>(
        part, out + (size_t)c * nc * DVV, ks, (size_t)nc * DVV / 4);
  }
}

// Round 11
// 261.812 us; speedup vs baseline: 1.0254x; 1.0254x over previous
//
#include <hip/hip_runtime.h>
#include <hip/hip_fp16.h>
#include <stdint.h>

typedef _Float16 f16;
typedef _Float16 f16x8 __attribute__((ext_vector_type(8)));
typedef float    f32x4 __attribute__((ext_vector_type(4)));
typedef int      i32x4 __attribute__((ext_vector_type(4)));

#define NQ 8192
#define NK 8192
#define DD 512
#define DVV 512
#define LOG2E 1.44269504f
#define KT256 (NK / 256)   // 32 key-tiles

// ---- async global->LDS stage of 64 lanes x 16B (wave-uniform LDS base, per-lane global src) ----
__device__ __forceinline__ void stage16(const void* g, void* ldsbase, int lane) {
#if __has_builtin(__builtin_amdgcn_global_load_lds)
  __builtin_amdgcn_global_load_lds((const __attribute__((address_space(1))) void*)g,
                                   (__attribute__((address_space(3))) void*)ldsbase, 16, 0, 0);
#else
  ((i32x4*)ldsbase)[lane] = *(const i32x4*)g;
#endif
}

// ---- fp32 -> f16 for K and Q in one launch ----
__global__ void conv_two(const float* __restrict__ srcA, f16* __restrict__ dstA,
                         const float* __restrict__ srcB, f16* __restrict__ dstB, int n8) {
  int i = blockIdx.x * 256 + threadIdx.x;
  const float* src;
  f16* dst;
  if (i < n8) { src = srcA; dst = dstA; }
  else        { src = srcB; dst = dstB; i -= n8; if (i >= n8) return; }
  const float4* s4 = (const float4*)src;
  float4 a = s4[2 * i], b = s4[2 * i + 1];
  float vv[8] = {a.x, a.y, a.z, a.w, b.x, b.y, b.z, b.w};
  f16 h8[8];
#pragma unroll
  for (int j = 0; j < 8; ++j) h8[j] = (f16)vv[j];
  *(f16x8*)(dst + (size_t)i * 8) = *(f16x8*)h8;
}

// ---- V fp32 [key][dv] -> f16 transposed [dv][key] ----
__global__ void conv_vT(const float* __restrict__ v, f16* __restrict__ vT) {
  __shared__ float t[64][65];
  int k0 = blockIdx.x * 64, d0 = blockIdx.y * 64;
#pragma unroll
  for (int e = 0; e < 16; ++e) {
    int idx = threadIdx.x + e * 256;
    int kr = idx >> 6, dc = idx & 63;
    t[kr][dc] = v[(size_t)(k0 + kr) * DVV + d0 + dc];
  }
  __syncthreads();
  int dl = threadIdx.x >> 2, seg = (threadIdx.x & 3) * 16;
  f16 tmp[16];
#pragma unroll
  for (int c = 0; c < 16; ++c) tmp[c] = (f16)t[seg + c][dl];
  f16* dst = vT + (size_t)(d0 + dl) * NK + k0 + seg;
  *(f16x8*)dst = *(f16x8*)tmp;
  *(f16x8*)(dst + 8) = *(f16x8*)(tmp + 8);
}

// ---- K1: S = Q*K^T plain f16, 256x256 tile, BK=64, 8 waves (2Mx4N), double-buffered
//      128KB LDS (R4 mainloop verbatim). Epilogue: exp2 softmax, DIRECT scatter from acc
//      with NONTEMPORAL stores into TILE-BLOCKED s16; transposed pm/ps.
__global__ __launch_bounds__(512, 2) void qk_kernel(
    const f16* __restrict__ q16, const f16* __restrict__ k16,
    f16* __restrict__ s16, float* __restrict__ pmT, float* __restrict__ psT,
    int nrows) {
  __shared__ f16 LS[65536];           // [buf][A 256x64 | B 256x64]
  __shared__ float red[2][4][128];
  const int tid = threadIdx.x, lane = tid & 63, wid = tid >> 6;
  const int wr = wid >> 2, wc = wid & 3;   // 2(M) x 4(N)
  const int bx = blockIdx.x, by = blockIdx.y;
  const int lo16 = lane & 15, hi4 = lane >> 4;

  f32x4 acc[8][4] = {};

  // staging: per wave 4 A-units + 4 B-units of (8 rows x 128B); src pre-swizzled, LDS linear
  const int srw = lane >> 3, sc8 = (lane & 7) ^ srw;
  const f16* aptr[4]; const f16* bptr[4]; int adst[4], bdst[4];
#pragma unroll
  for (int u = 0; u < 4; ++u) {
    int r = wid * 32 + u * 8 + srw;
    aptr[u] = q16 + (size_t)(by * 256 + r) * DD + sc8 * 8;
    bptr[u] = k16 + (size_t)(bx * 256 + r) * DD + sc8 * 8;
    adst[u] = (wid * 32 + u * 8) * 64;
    bdst[u] = adst[u] + 16384;
  }
  // fragment offsets (proven conflict-free: 128B rows, unit ^ (row&7))
  int aoff[8][2], boff[4][2];
#pragma unroll
  for (int m = 0; m < 8; ++m)
#pragma unroll
    for (int kk = 0; kk < 2; ++kk) {
      int row = wr * 128 + m * 16 + lo16;
      aoff[m][kk] = row * 64 + (((kk * 4 + hi4) ^ (row & 7)) << 3);
    }
#pragma unroll
  for (int n = 0; n < 4; ++n)
#pragma unroll
    for (int kk = 0; kk < 2; ++kk) {
      int row = wc * 64 + n * 16 + lo16;
      boff[n][kk] = 16384 + row * 64 + (((kk * 4 + hi4) ^ (row & 7)) << 3);
    }

#define STG(t2, buf)                                                        \
  do {                                                                      \
    _Pragma("unroll") for (int u = 0; u < 4; ++u) {                         \
      stage16(aptr[u] + (t2) * 64, LS + (buf) * 32768 + adst[u], lane);     \
      stage16(bptr[u] + (t2) * 64, LS + (buf) * 32768 + bdst[u], lane);     \
    }                                                                       \
  } while (0)

  STG(0, 0);
  asm volatile("s_waitcnt vmcnt(0)" ::: "memory");
  __builtin_amdgcn_s_barrier();
  asm volatile("" ::: "memory");

  for (int t = 0; t < 8; ++t) {
    const int cur = t & 1;
    if (t < 7) STG(t + 1, cur ^ 1);
    const f16* Bb = LS + cur * 32768;
    f16x8 bf[2][4];
#pragma unroll
    for (int n = 0; n < 4; ++n)
#pragma unroll
      for (int kk = 0; kk < 2; ++kk) bf[kk][n] = *(const f16x8*)&Bb[boff[n][kk]];
#pragma unroll
    for (int h = 0; h < 2; ++h) {
      f16x8 af[4][2];
#pragma unroll
      for (int mi = 0; mi < 4; ++mi)
#pragma unroll
        for (int kk = 0; kk < 2; ++kk) af[mi][kk] = *(const f16x8*)&Bb[aoff[h * 4 + mi][kk]];
      __builtin_amdgcn_s_setprio(1);
#pragma unroll
      for (int mi = 0; mi < 4; ++mi)
#pragma unroll
        for (int n = 0; n < 4; ++n) {
          acc[h * 4 + mi][n] =
              __builtin_amdgcn_mfma_f32_16x16x32_f16(af[mi][0], bf[0][n], acc[h * 4 + mi][n], 0, 0, 0);
          acc[h * 4 + mi][n] =
              __builtin_amdgcn_mfma_f32_16x16x32_f16(af[mi][1], bf[1][n], acc[h * 4 + mi][n], 0, 0, 0);
        }
      __builtin_amdgcn_s_setprio(0);
    }
    asm volatile("s_waitcnt vmcnt(0)" ::: "memory");
    __builtin_amdgcn_s_barrier();
    asm volatile("" ::: "memory");
  }
#undef STG

  // ---- epilogue: tile-local softmax (exp2) + direct nt-scatter into tiled s16 ----
  float rmax[8][4];
#pragma unroll
  for (int i = 0; i < 8; ++i)
#pragma unroll
    for (int r = 0; r < 4; ++r) {
      float m = fmaxf(fmaxf(acc[i][0][r], acc[i][1][r]), fmaxf(acc[i][2][r], acc[i][3][r]));
#pragma unroll
      for (int d = 1; d < 16; d <<= 1) m = fmaxf(m, __shfl_xor(m, d, 64));
      rmax[i][r] = m;
    }
  if (lo16 == 0) {
#pragma unroll
    for (int i = 0; i < 8; ++i)
#pragma unroll
      for (int r = 0; r < 4; ++r) red[wr][wc][i * 16 + hi4 * 4 + r] = rmax[i][r];
  }
  __syncthreads();
  float pmv[8][4];
#pragma unroll
  for (int i = 0; i < 8; ++i)
#pragma unroll
    for (int r = 0; r < 4; ++r) {
      int rl = i * 16 + hi4 * 4 + r;
      pmv[i][r] = fmaxf(fmaxf(red[wr][0][rl], red[wr][1][rl]),
                        fmaxf(red[wr][2][rl], red[wr][3][rl]));
    }
  __syncthreads();
  // exp + row-sum + nontemporal scatter into the block's private 128KB tile
  f16* tile = s16 + ((size_t)(by * KT256 + bx) << 16);
  float rsum[8][4];
#pragma unroll
  for (int i = 0; i < 8; ++i)
#pragma unroll
    for (int r = 0; r < 4; ++r) {
      int qloc = wr * 128 + i * 16 + hi4 * 4 + r;
      float s = 0.f;
#pragma unroll
      for (int j = 0; j < 4; ++j) {
        float p = exp2f((acc[i][j][r] - pmv[i][r]) * LOG2E);
        s += p;
        int kloc = wc * 64 + j * 16 + lo16;
        __builtin_nontemporal_store((f16)p, tile + qloc * 256 + kloc);
      }
#pragma unroll
      for (int d = 1; d < 16; d <<= 1) s += __shfl_xor(s, d, 64);
      rsum[i][r] = s;
    }
  if (lo16 == 0) {
#pragma unroll
    for (int i = 0; i < 8; ++i)
#pragma unroll
      for (int r = 0; r < 4; ++r) red[wr][wc][i * 16 + hi4 * 4 + r] = rsum[i][r];
  }
  __syncthreads();
  // pm/ps transposed store [bx][row]
  if (wc == 0 && lo16 == 0) {
#pragma unroll
    for (int i = 0; i < 8; ++i)
#pragma unroll
      for (int r = 0; r < 4; ++r) {
        int rl = i * 16 + hi4 * 4 + r;
        size_t grow = (size_t)(by * 256 + wr * 128 + rl);
        pmT[(size_t)bx * nrows + grow] = pmv[i][r];
        psT[(size_t)bx * nrows + grow] = red[wr][0][rl] + red[wr][1][rl] +
                                         red[wr][2][rl] + red[wr][3][rl];
      }
  }
}

// ---- K2: per-row combine of 32 tile partials (transposed layout) ----
__global__ void red_kernel(const float* __restrict__ pmT, const float* __restrict__ psT,
                           float* __restrict__ coefT, int nrows) {
  int row = blockIdx.x * 8 + (threadIdx.x >> 5);
  int t = threadIdx.x & 31;
  float pmt = pmT[(size_t)t * nrows + row];
  float m = pmt;
#pragma unroll
  for (int d = 1; d < 32; d <<= 1) m = fmaxf(m, __shfl_xor(m, d, 32));
  float e = exp2f((pmt - m) * LOG2E);
  float l = psT[(size_t)t * nrows + row] * e;
#pragma unroll
  for (int d = 1; d < 32; d <<= 1) l += __shfl_xor(l, d, 32);
  coefT[(size_t)t * nrows + row] = e / l;
}

// ---- K3: O_partial = (coef*p16) @ V16^T. 128x128 tile, BK=64, K-split over blockIdx.z.
//      p16 read from TILE-BLOCKED layout. ----
__global__ __launch_bounds__(256, 2) void pv_kernel(
    const f16* __restrict__ p16, const float* __restrict__ coefT,
    const f16* __restrict__ vT, float* __restrict__ dst,
    int steps, size_t zstride, int nrows) {
  __shared__ f16 lsA[2][128 * 64];
  __shared__ f16 lsB[2][128 * 64];
  const int tid = threadIdx.x, lane = tid & 63, wid = tid >> 6;
  const int lo16 = lane & 15, hi4 = lane >> 4;
  const int wr = wid >> 1, wc = wid & 1;
  const int bx = blockIdx.x, by = blockIdx.y, bz = blockIdx.z;
  const int g0 = bz * steps;
  f32x4 acc[4][4] = {};

  const int arow0 = tid >> 3, acol = tid & 7;
  const int srw = lane >> 3;
  const int sc = (lane & 7) ^ srw;

  // tiled-layout base per u: tile row qt=r>>8, in-tile row qloc=r&255
  size_t qtb[4];
#pragma unroll
  for (int u = 0; u < 4; ++u) {
    int r = by * 128 + u * 32 + arow0;
    qtb[u] = ((size_t)(r >> 8) * KT256 << 16) + (size_t)(r & 255) * 256 + acol * 8;
  }

  f16x8 va[4];
  float scv[4];

#define PV_LOADA(g)                                                           \
  do {                                                                        \
    _Pragma("unroll") for (int u = 0; u < 4; ++u)                             \
        va[u] = *(const f16x8*)(p16 + qtb[u] + ((size_t)((g) >> 2) << 16) +   \
                                ((g) & 3) * 64);                              \
    _Pragma("unroll") for (int u = 0; u < 4; ++u)                             \
        scv[u] = coefT[(size_t)((g) >> 2) * nrows + by * 128 + u * 32 + arow0]; \
  } while (0)

  PV_LOADA(g0);
#pragma unroll
  for (int i = 0; i < 4; ++i) {
    int unit = wid * 4 + i;
    int row = unit * 8 + srw;
    stage16(vT + (size_t)(bx * 128 + row) * NK + (size_t)g0 * 64 + sc * 8,
            &lsB[0][unit * 512], lane);
  }
#pragma unroll
  for (int u = 0; u < 4; ++u) {
    int row = u * 32 + arow0;
    f16x8 vv = va[u] * (f16)scv[u];
    *(f16x8*)&lsA[0][row * 64 + ((acol ^ (row & 7)) << 3)] = vv;
  }
  __syncthreads();

  for (int s = 0; s < steps; ++s) {
    const int cur = s & 1, nxt = cur ^ 1;
    const int g = g0 + s;
    if (s + 1 < steps) {
      PV_LOADA(g + 1);
#pragma unroll
      for (int i = 0; i < 4; ++i) {
        int unit = wid * 4 + i;
        int row = unit * 8 + srw;
        stage16(vT + (size_t)(bx * 128 + row) * NK + (size_t)(g + 1) * 64 + sc * 8,
                &lsB[nxt][unit * 512], lane);
      }
    }
#pragma unroll
    for (int ks = 0; ks < 2; ++ks) {
      f16x8 af[4], bf[4];
#pragma unroll
      for (int i = 0; i < 4; ++i) {
        int row = wr * 64 + i * 16 + lo16;
        af[i] = *(const f16x8*)&lsA[cur][row * 64 + (((ks * 4 + hi4) ^ (row & 7)) << 3)];
      }
#pragma unroll
      for (int j = 0; j < 4; ++j) {
        int dv = wc * 64 + j * 16 + lo16;
        bf[j] = *(const f16x8*)&lsB[cur][dv * 64 + (((ks * 4 + hi4) ^ (dv & 7)) << 3)];
      }
#pragma unroll
      for (int i = 0; i < 4; ++i)
#pragma unroll
        for (int j = 0; j < 4; ++j)
          acc[i][j] = __builtin_amdgcn_mfma_f32_16x16x32_f16(af[i], bf[j], acc[i][j], 0, 0, 0);
    }
    if (s + 1 < steps) {
#pragma unroll
      for (int u = 0; u < 4; ++u) {
        int row = u * 32 + arow0;
        f16x8 vv = va[u] * (f16)scv[u];
        *(f16x8*)&lsA[nxt][row * 64 + ((acol ^ (row & 7)) << 3)] = vv;
      }
    }
    __syncthreads();
  }
#undef PV_LOADA

  float* o = dst + (size_t)bz * zstride;
#pragma unroll
  for (int i = 0; i < 4; ++i)
#pragma unroll
    for (int j = 0; j < 4; ++j)
#pragma unroll
      for (int r = 0; r < 4; ++r)
        o[(size_t)(by * 128 + wr * 64 + i * 16 + hi4 * 4 + r) * DVV +
          bx * 128 + wc * 64 + j * 16 + lo16] = acc[i][j][r];
}

// ---- K4: sum K-split partials ----
__global__ void reduce_out(const float* __restrict__ part, float* __restrict__ out,
                           int ks, size_t n4) {
  size_t i = (size_t)blockIdx.x * 256 + threadIdx.x;
  if (i >= n4) return;
  float4 a = ((const float4*)part)[i];
  for (int z = 1; z < ks; ++z) {
    float4 b = ((const float4*)(part + z * n4 * 4))[i];
    a.x += b.x; a.y += b.y; a.z += b.z; a.w += b.w;
  }
  ((float4*)out)[i] = a;
}

__global__ void zero_out(float* o, int n) {
  int i = blockIdx.x * 256 + threadIdx.x;
  if (i < n) o[i] = 0.f;
}

extern "C" void kernel_launch(void* const* d_in, const int* in_sizes, int n_in,
                              void* d_out, int out_size, void* d_ws, size_t ws_size,
                              hipStream_t stream) {
  (void)in_sizes; (void)n_in; (void)out_size;
  const float* Q = (const float*)d_in[0];
  const float* K = (const float*)d_in[1];
  const float* V = (const float*)d_in[2];
  float* out = (float*)d_out;

  const size_t sz16 = (size_t)NK * DD * 2;                  // 8 MB
  const size_t fixedB = 2 * sz16;                           // k16, vT
  const size_t perRow = 1024 + 32 * 4 * 3 + (size_t)NK * 2; // q16 + pmT/psT/coefT + s16 = 17792
  const size_t partB = (size_t)16384 * DVV * 4;             // 32 MB (ks*nc == 16384)
  int nc = 0;
  for (int cand = 8192; cand >= 1024; cand >>= 1)
    if (fixedB + (size_t)cand * perRow + partB <= ws_size) { nc = cand; break; }
  if (nc == 0) {
    zero_out<<<(NQ * DVV + 255) / 256, 256, 0, stream>>>(out, NQ * DVV);
    return;
  }
  const int ks = 16384 / nc;       // pv K-split so grid = 4 * (nc/128) * ks = 512 blocks
  const int steps = 128 / ks;      // 64-key steps per z

  char* w = (char*)d_ws;
  f16* k16 = (f16*)w;
  f16* vT = (f16*)(w + sz16);
  char* p = w + fixedB;
  f16* q16 = (f16*)p;       p += (size_t)nc * 1024;
  float* pmT = (float*)p;   p += (size_t)nc * 128;
  float* psT = (float*)p;   p += (size_t)nc * 128;
  float* coefT = (float*)p; p += (size_t)nc * 128;
  f16* s16 = (f16*)p;       p += (size_t)nc * NK * 2;
  float* part = (float*)p;

  conv_vT<<<dim3(NK / 64, DVV / 64), 256, 0, stream>>>(V, vT);

  for (int c = 0; c < NQ / nc; ++c) {
    if (c == 0) {
      // first chunk: convert K and Q together in one launch
      int n8k = NK * DD / 8;
      int n8q = nc * DD / 8;
      conv_two<<<(n8k + n8q + 255) / 256, 256, 0, stream>>>(K, k16, Q, q16, n8k);
    } else {
      conv_two<<<(nc * DD / 8 * 2 + 255) / 256, 256, 0, stream>>>(
          Q + (size_t)c * nc * DD, q16, Q + (size_t)c * nc * DD, q16, nc * DD / 8);
    }
    qk_kernel<<<dim3(NK / 256, nc / 256), 512, 0, stream>>>(q16, k16, s16, pmT, psT, nc);
    red_kernel<<<nc / 8, 256, 0, stream>>>(pmT, psT, coefT, nc);
    pv_kernel<<<dim3(DVV / 128, nc / 128, ks), 256, 0, stream>>>(
        s16, coefT, vT, part, steps, (size_t)nc * DVV, nc);
    reduce_out<<<(int)(((size_t)nc * DVV / 4 + 255) / 256), 256, 0, stream>>>(
        part, out + (size_t)c * nc * DVV, ks, (size_t)nc * DVV / 4);
  }
}